// Round 1
// baseline (12446.793 us; speedup 1.0000x reference)
//
#include <hip/hip_runtime.h>
#include <math.h>

#define NTHR 256
#define BT 4

__global__ __launch_bounds__(NTHR, 1)
void odernn_kernel(const float* __restrict__ quat,   // [1024][64][4]
                   const float* __restrict__ W1,     // [68][256]
                   const float* __restrict__ b1,     // [256]
                   const float* __restrict__ W2,     // [256][256]
                   const float* __restrict__ b2,     // [256]
                   const float* __restrict__ W3,     // [256][64]
                   const float* __restrict__ b3,     // [64]
                   float* __restrict__ out)          // [1024*64] hfinal, then [1024][64][8][64] traj
{
    __shared__ __align__(16) float sW1h[64 * 256];   // 64 KB
    __shared__ __align__(16) float sW3[256 * 64];    // 64 KB
    __shared__ __align__(16) float sRed[2048];       // 8 KB (shared by L2/L3 partials)
    __shared__ __align__(16) float sH1[4][256];      // 4 KB
    __shared__ __align__(16) float sH2[4][256];      // 4 KB
    __shared__ __align__(16) float sC1[4][256];      // 4 KB
    __shared__ __align__(16) float sY[4][64];        // 1 KB
    __shared__ float sB1[256];
    __shared__ float sB2[256];
    __shared__ float sB3[64];

    const int t  = threadIdx.x;
    const int b0 = blockIdx.x * BT;

    // ---- stage loop-invariant weights into LDS ----
    for (int idx = t; idx < 64 * 256; idx += NTHR) sW1h[idx] = W1[idx];
    for (int idx = t; idx < 256 * 64; idx += NTHR) sW3[idx]  = W3[idx];
    sB1[t] = b1[t];
    sB2[t] = b2[t];
    if (t < 64) sB3[t] = b3[t];

    // owner mapping for RK4 state: thread t owns (batch rb, state dim rj)
    const int rb = t >> 6;         // 0..3
    const int rj = t & 63;         // 0..63
    float rH  = (rj == 0) ? 1.0f : 0.0f;
    float rk1 = 0.0f, rk2 = 0.0f, rk3 = 0.0f;
    sY[rb][rj] = rH;
    __syncthreads();

    const float2* __restrict__ W2v = (const float2*)W2;
    const float dt = 1.0f / 7.0f;

    // layer-1 mapping: 2 j's x 2 b's per thread, full K=64
    const int jp = (t & 127) * 2;
    const int bp = (t >> 7) * 2;
    // layer-2 mapping: 2 j's x 4 b's per thread, K split 2-way (dup-free W2 reads)
    const int u2  = t & 127;       // j-pair index
    const int ks2 = t >> 7;        // 0/1
    // layer-3 mapping: 2 j's x 4 b's per thread, K split 8-way
    const int jp3 = (t & 31) * 2;
    const int ks3 = t >> 5;        // 0..7

    float* __restrict__ traj = out + 1024 * 64;

    for (int s = 0; s < 64; ++s) {
        // ---- per-token constant: c1 = b1 + q @ W1[64:68,:] ----
        {
            float acc[4];
            #pragma unroll
            for (int bb = 0; bb < 4; ++bb) acc[bb] = sB1[t];
            #pragma unroll
            for (int m = 0; m < 4; ++m) {
                float wq = W1[(64 + m) * 256 + t];
                #pragma unroll
                for (int bb = 0; bb < 4; ++bb) {
                    float q = quat[((size_t)(b0 + bb) * 64 + s) * 4 + m];
                    acc[bb] = fmaf(q, wq, acc[bb]);
                }
            }
            #pragma unroll
            for (int bb = 0; bb < 4; ++bb) sC1[bb][t] = acc[bb];
        }
        // record initial state for this token (rH is a register; no hazard)
        traj[(((size_t)(b0 + rb) * 64 + s) * 8 + 0) * 64 + rj] = rH;
        __syncthreads();

        for (int step = 1; step < 8; ++step) {
            #pragma unroll
            for (int mode = 1; mode <= 4; ++mode) {
                // ---------- layer 1: h1 = tanh(y @ W1h + c1) ----------
                {
                    float a00 = sC1[bp][jp],     a01 = sC1[bp][jp + 1];
                    float a10 = sC1[bp + 1][jp], a11 = sC1[bp + 1][jp + 1];
                    #pragma unroll
                    for (int i = 0; i < 64; i += 4) {
                        float4 y0 = *(const float4*)&sY[bp][i];
                        float4 y1 = *(const float4*)&sY[bp + 1][i];
                        #pragma unroll
                        for (int r = 0; r < 4; ++r) {
                            float2 w = *(const float2*)&sW1h[(i + r) * 256 + jp];
                            float y0r = ((const float*)&y0)[r];
                            float y1r = ((const float*)&y1)[r];
                            a00 = fmaf(y0r, w.x, a00);
                            a01 = fmaf(y0r, w.y, a01);
                            a10 = fmaf(y1r, w.x, a10);
                            a11 = fmaf(y1r, w.y, a11);
                        }
                    }
                    sH1[bp][jp]         = tanhf(a00);
                    sH1[bp][jp + 1]     = tanhf(a01);
                    sH1[bp + 1][jp]     = tanhf(a10);
                    sH1[bp + 1][jp + 1] = tanhf(a11);
                }
                __syncthreads();
                // ---------- layer 2 partial: h1 @ W2 (K-split, W2 streamed) ----------
                {
                    float a[4][2];
                    #pragma unroll
                    for (int bb = 0; bb < 4; ++bb) { a[bb][0] = 0.0f; a[bb][1] = 0.0f; }
                    const int ibase = ks2 * 128;
                    #pragma unroll 4
                    for (int i4 = 0; i4 < 128; i4 += 4) {
                        float4 yv[4];
                        #pragma unroll
                        for (int bb = 0; bb < 4; ++bb)
                            yv[bb] = *(const float4*)&sH1[bb][ibase + i4];
                        #pragma unroll
                        for (int r = 0; r < 4; ++r) {
                            float2 w = W2v[(size_t)(ibase + i4 + r) * 128 + u2];
                            #pragma unroll
                            for (int bb = 0; bb < 4; ++bb) {
                                float yr = ((const float*)&yv[bb])[r];
                                a[bb][0] = fmaf(yr, w.x, a[bb][0]);
                                a[bb][1] = fmaf(yr, w.y, a[bb][1]);
                            }
                        }
                    }
                    #pragma unroll
                    for (int bb = 0; bb < 4; ++bb)
                        *(float2*)&sRed[(ks2 * 4 + bb) * 256 + u2 * 2] =
                            make_float2(a[bb][0], a[bb][1]);
                }
                __syncthreads();
                // ---------- layer 2 reduce + tanh ----------
                {
                    #pragma unroll
                    for (int bb = 0; bb < 4; ++bb) {
                        float v = sRed[bb * 256 + t] + sRed[(4 + bb) * 256 + t] + sB2[t];
                        sH2[bb][t] = tanhf(v);
                    }
                }
                __syncthreads();
                // ---------- layer 3 partial: h2 @ W3 (K-split 8-way) ----------
                {
                    float a[4][2];
                    #pragma unroll
                    for (int bb = 0; bb < 4; ++bb) { a[bb][0] = 0.0f; a[bb][1] = 0.0f; }
                    const int ibase = ks3 * 32;
                    #pragma unroll
                    for (int i4 = 0; i4 < 32; i4 += 4) {
                        float4 yv[4];
                        #pragma unroll
                        for (int bb = 0; bb < 4; ++bb)
                            yv[bb] = *(const float4*)&sH2[bb][ibase + i4];
                        #pragma unroll
                        for (int r = 0; r < 4; ++r) {
                            float2 w = *(const float2*)&sW3[(ibase + i4 + r) * 64 + jp3];
                            #pragma unroll
                            for (int bb = 0; bb < 4; ++bb) {
                                float yr = ((const float*)&yv[bb])[r];
                                a[bb][0] = fmaf(yr, w.x, a[bb][0]);
                                a[bb][1] = fmaf(yr, w.y, a[bb][1]);
                            }
                        }
                    }
                    #pragma unroll
                    for (int bb = 0; bb < 4; ++bb)
                        *(float2*)&sRed[(ks3 * 4 + bb) * 64 + jp3] =
                            make_float2(a[bb][0], a[bb][1]);
                }
                __syncthreads();
                // ---------- layer 3 reduce + RK4 (3/8-rule) state update ----------
                {
                    float k = sB3[rj];
                    #pragma unroll
                    for (int ksr = 0; ksr < 8; ++ksr)
                        k += sRed[(ksr * 4 + rb) * 64 + rj];
                    float ynew;
                    if (mode == 1) {
                        rk1 = k;
                        ynew = fmaf(dt * (1.0f / 3.0f), rk1, rH);
                    } else if (mode == 2) {
                        rk2 = k;
                        ynew = fmaf(dt, rk2 - rk1 * (1.0f / 3.0f), rH);
                    } else if (mode == 3) {
                        rk3 = k;
                        ynew = fmaf(dt, rk1 - rk2 + rk3, rH);
                    } else {
                        rH = fmaf(dt * 0.125f, rk1 + 3.0f * (rk2 + rk3) + k, rH);
                        ynew = rH;
                        traj[(((size_t)(b0 + rb) * 64 + s) * 8 + step) * 64 + rj] = rH;
                    }
                    sY[rb][rj] = ynew;
                }
                __syncthreads();
            }
        }
    }
    out[(size_t)(b0 + rb) * 64 + rj] = rH;
}

extern "C" void kernel_launch(void* const* d_in, const int* in_sizes, int n_in,
                              void* d_out, int out_size, void* d_ws, size_t ws_size,
                              hipStream_t stream) {
    const float* quat = (const float*)d_in[0];
    const float* W1   = (const float*)d_in[1];
    const float* b1   = (const float*)d_in[2];
    const float* W2   = (const float*)d_in[3];
    const float* b2   = (const float*)d_in[4];
    const float* W3   = (const float*)d_in[5];
    const float* b3   = (const float*)d_in[6];
    float* out = (float*)d_out;

    odernn_kernel<<<1024 / BT, NTHR, 0, stream>>>(quat, W1, b1, W2, b2, W3, b3, out);
}

// Round 2
// 8276.985 us; speedup vs baseline: 1.5038x; 1.5038x over previous
//
#include <hip/hip_runtime.h>
#include <math.h>

#define NTHR 512
#define BT 4

__device__ __forceinline__ float fast_tanh(float x) {
    float ax = fabsf(x);
    float e  = __expf(-2.0f * ax);                       // in (0,1], never overflows
    float r  = (1.0f - e) * __builtin_amdgcn_rcpf(1.0f + e);
    return copysignf(r, x);
}

__global__ __launch_bounds__(NTHR, 2)
void odernn_kernel(const float* __restrict__ quat,   // [1024][64][4]
                   const float* __restrict__ W1,     // [68][256]
                   const float* __restrict__ b1,     // [256]
                   const float* __restrict__ W2,     // [256][256]
                   const float* __restrict__ b2,     // [256]
                   const float* __restrict__ W3,     // [256][64]
                   const float* __restrict__ b3,     // [64]
                   float* __restrict__ out)          // [1024*64] hfinal, then [1024][64][8][64] traj
{
    // LDS: activations + partial-sum buffers only (weights live in registers / L2)
    __shared__ __align__(16) float sRed[8192];    // 32 KB: L2 partials [8][4][256] / L3 partials [32][4][64]
    __shared__ __align__(16) float sH1[4][256];   // 4 KB
    __shared__ __align__(16) float sH2[4][256];   // 4 KB
    __shared__ __align__(16) float sC1[4][256];   // 4 KB
    __shared__ __align__(16) float sY[4][64];     // 1 KB

    const int t  = threadIdx.x;
    const int b0 = blockIdx.x * BT;

    // ---- thread mappings ----
    // L1 / L2-reduce: (column j1, batch-half bh)
    const int j1 = t & 255;
    const int bh = t >> 8;            // 0 -> batches {0,1}, 1 -> {2,3}
    const int bA = bh * 2, bB = bA + 1;
    // L2 partial: j-quad u2, K-slice ks2 (8 slices of 32)
    const int u2  = t & 63;
    const int j02 = u2 * 4;
    const int kb2 = (t >> 6) * 32;
    // L3 partial: j-quad u3, K-slice ks3 (32 slices of 8)
    const int u3  = t & 15;
    const int j03 = u3 * 4;
    const int ks3 = t >> 4;
    const int kb3 = ks3 * 8;
    // RK4 / L3-reduce owner (t < 256): (batch rb, state dim rj)
    const int rb = (t >> 6) & 3;
    const int rj = t & 63;

    // ---- eval-invariant weights into REGISTERS (dup-free K-slice ownership) ----
    float w1r[64];                    // W1h[k][j1], k = 0..63
    #pragma unroll
    for (int k = 0; k < 64; ++k) w1r[k] = W1[k * 256 + j1];

    float w3r[32];                    // W3[kb3+k][j03+jj], k=0..7, jj=0..3
    #pragma unroll
    for (int k = 0; k < 8; ++k) {
        float4 w = *(const float4*)&W3[(kb3 + k) * 64 + j03];
        w3r[k * 4 + 0] = w.x; w3r[k * 4 + 1] = w.y;
        w3r[k * 4 + 2] = w.z; w3r[k * 4 + 3] = w.w;
    }
    float w1q[4];                     // W1[64+m][j1] (q-part of layer 1)
    #pragma unroll
    for (int m = 0; m < 4; ++m) w1q[m] = W1[(64 + m) * 256 + j1];

    const float rb1 = b1[j1];
    const float rb2 = b2[j1];
    const float rb3 = b3[rj];

    float rH  = (rj == 0) ? 1.0f : 0.0f;   // meaningful for t<256 only
    float rk1 = 0.0f, rk2 = 0.0f, rk3 = 0.0f;
    if (t < 256) sY[rb][rj] = rH;

    const float4* __restrict__ W2v4 = (const float4*)W2;
    const float dt = 1.0f / 7.0f;
    float* __restrict__ traj = out + 1024 * 64;

    for (int s = 0; s < 64; ++s) {
        // ---- per-token: c1 = b1 + q @ W1q ; record initial state ----
        if (t < 256) {
            float4 q0 = *(const float4*)&quat[((size_t)(b0 + 0) * 64 + s) * 4];
            float4 q1 = *(const float4*)&quat[((size_t)(b0 + 1) * 64 + s) * 4];
            float4 q2 = *(const float4*)&quat[((size_t)(b0 + 2) * 64 + s) * 4];
            float4 q3 = *(const float4*)&quat[((size_t)(b0 + 3) * 64 + s) * 4];
            sC1[0][t] = fmaf(q0.x, w1q[0], fmaf(q0.y, w1q[1], fmaf(q0.z, w1q[2], fmaf(q0.w, w1q[3], rb1))));
            sC1[1][t] = fmaf(q1.x, w1q[0], fmaf(q1.y, w1q[1], fmaf(q1.z, w1q[2], fmaf(q1.w, w1q[3], rb1))));
            sC1[2][t] = fmaf(q2.x, w1q[0], fmaf(q2.y, w1q[1], fmaf(q2.z, w1q[2], fmaf(q2.w, w1q[3], rb1))));
            sC1[3][t] = fmaf(q3.x, w1q[0], fmaf(q3.y, w1q[1], fmaf(q3.z, w1q[2], fmaf(q3.w, w1q[3], rb1))));
            traj[(((size_t)(b0 + rb) * 64 + s) * 8 + 0) * 64 + rj] = rH;
        }
        __syncthreads();

        for (int step = 1; step < 8; ++step) {
            #pragma unroll
            for (int mode = 1; mode <= 4; ++mode) {
                // ---------- A: h1 = tanh(y @ W1h + c1)  (W1h in regs, direct) ----------
                {
                    float a0 = sC1[bA][j1];
                    float a1 = sC1[bB][j1];
                    const float4* y4A = (const float4*)&sY[bA][0];
                    const float4* y4B = (const float4*)&sY[bB][0];
                    #pragma unroll
                    for (int k4 = 0; k4 < 16; ++k4) {
                        float4 y0 = y4A[k4];
                        float4 y1 = y4B[k4];
                        a0 = fmaf(y0.x, w1r[k4 * 4 + 0], a0);
                        a0 = fmaf(y0.y, w1r[k4 * 4 + 1], a0);
                        a0 = fmaf(y0.z, w1r[k4 * 4 + 2], a0);
                        a0 = fmaf(y0.w, w1r[k4 * 4 + 3], a0);
                        a1 = fmaf(y1.x, w1r[k4 * 4 + 0], a1);
                        a1 = fmaf(y1.y, w1r[k4 * 4 + 1], a1);
                        a1 = fmaf(y1.z, w1r[k4 * 4 + 2], a1);
                        a1 = fmaf(y1.w, w1r[k4 * 4 + 3], a1);
                    }
                    sH1[bA][j1] = fast_tanh(a0);
                    sH1[bB][j1] = fast_tanh(a1);
                }
                __syncthreads();
                // ---------- B: layer-2 partials (W2 streamed from L2, dup-free) ----------
                {
                    float acc[4][4];
                    #pragma unroll
                    for (int bb = 0; bb < 4; ++bb)
                        #pragma unroll
                        for (int jj = 0; jj < 4; ++jj) acc[bb][jj] = 0.0f;
                    #pragma unroll
                    for (int k4 = 0; k4 < 8; ++k4) {
                        const int k = kb2 + k4 * 4;
                        float4 y0 = *(const float4*)&sH1[0][k];
                        float4 y1 = *(const float4*)&sH1[1][k];
                        float4 y2 = *(const float4*)&sH1[2][k];
                        float4 y3 = *(const float4*)&sH1[3][k];
                        #pragma unroll
                        for (int r = 0; r < 4; ++r) {
                            float4 w = W2v4[(size_t)(k + r) * 64 + u2];
                            float f0 = ((const float*)&y0)[r];
                            float f1 = ((const float*)&y1)[r];
                            float f2 = ((const float*)&y2)[r];
                            float f3 = ((const float*)&y3)[r];
                            acc[0][0] = fmaf(f0, w.x, acc[0][0]); acc[0][1] = fmaf(f0, w.y, acc[0][1]);
                            acc[0][2] = fmaf(f0, w.z, acc[0][2]); acc[0][3] = fmaf(f0, w.w, acc[0][3]);
                            acc[1][0] = fmaf(f1, w.x, acc[1][0]); acc[1][1] = fmaf(f1, w.y, acc[1][1]);
                            acc[1][2] = fmaf(f1, w.z, acc[1][2]); acc[1][3] = fmaf(f1, w.w, acc[1][3]);
                            acc[2][0] = fmaf(f2, w.x, acc[2][0]); acc[2][1] = fmaf(f2, w.y, acc[2][1]);
                            acc[2][2] = fmaf(f2, w.z, acc[2][2]); acc[2][3] = fmaf(f2, w.w, acc[2][3]);
                            acc[3][0] = fmaf(f3, w.x, acc[3][0]); acc[3][1] = fmaf(f3, w.y, acc[3][1]);
                            acc[3][2] = fmaf(f3, w.z, acc[3][2]); acc[3][3] = fmaf(f3, w.w, acc[3][3]);
                        }
                    }
                    // sRed as [8][4][256]: contiguous 16B per lane -> conflict-free
                    const int base = (t >> 6) * 1024;   // ks2*4*256
                    #pragma unroll
                    for (int bb = 0; bb < 4; ++bb)
                        *(float4*)&sRed[base + bb * 256 + j02] =
                            make_float4(acc[bb][0], acc[bb][1], acc[bb][2], acc[bb][3]);
                }
                __syncthreads();
                // ---------- C: layer-2 reduce + tanh ----------
                {
                    float v0a = rb2, v0b = 0.0f, v1a = rb2, v1b = 0.0f;
                    #pragma unroll
                    for (int ks = 0; ks < 8; ks += 2) {
                        v0a += sRed[(ks * 4 + bA) * 256 + j1];
                        v1a += sRed[(ks * 4 + bB) * 256 + j1];
                        v0b += sRed[((ks + 1) * 4 + bA) * 256 + j1];
                        v1b += sRed[((ks + 1) * 4 + bB) * 256 + j1];
                    }
                    sH2[bA][j1] = fast_tanh(v0a + v0b);
                    sH2[bB][j1] = fast_tanh(v1a + v1b);
                }
                __syncthreads();
                // ---------- D: layer-3 partials (W3 in regs) ----------
                {
                    float acc[4][4];
                    #pragma unroll
                    for (int bb = 0; bb < 4; ++bb)
                        #pragma unroll
                        for (int jj = 0; jj < 4; ++jj) acc[bb][jj] = 0.0f;
                    #pragma unroll
                    for (int k4 = 0; k4 < 2; ++k4) {
                        const int k = kb3 + k4 * 4;
                        float4 y0 = *(const float4*)&sH2[0][k];
                        float4 y1 = *(const float4*)&sH2[1][k];
                        float4 y2 = *(const float4*)&sH2[2][k];
                        float4 y3 = *(const float4*)&sH2[3][k];
                        #pragma unroll
                        for (int r = 0; r < 4; ++r) {
                            const int wi = (k4 * 4 + r) * 4;
                            float f0 = ((const float*)&y0)[r];
                            float f1 = ((const float*)&y1)[r];
                            float f2 = ((const float*)&y2)[r];
                            float f3 = ((const float*)&y3)[r];
                            #pragma unroll
                            for (int jj = 0; jj < 4; ++jj) {
                                acc[0][jj] = fmaf(f0, w3r[wi + jj], acc[0][jj]);
                                acc[1][jj] = fmaf(f1, w3r[wi + jj], acc[1][jj]);
                                acc[2][jj] = fmaf(f2, w3r[wi + jj], acc[2][jj]);
                                acc[3][jj] = fmaf(f3, w3r[wi + jj], acc[3][jj]);
                            }
                        }
                    }
                    // sRed as [32][4][64]
                    #pragma unroll
                    for (int bb = 0; bb < 4; ++bb)
                        *(float4*)&sRed[(ks3 * 4 + bb) * 64 + j03] =
                            make_float4(acc[bb][0], acc[bb][1], acc[bb][2], acc[bb][3]);
                }
                __syncthreads();
                // ---------- E: layer-3 reduce + RK4 (3/8-rule) ----------
                if (t < 256) {
                    float s0 = rb3, s1 = 0.0f, s2 = 0.0f, s3 = 0.0f;
                    #pragma unroll
                    for (int ks = 0; ks < 32; ks += 4) {
                        s0 += sRed[((ks + 0) * 4 + rb) * 64 + rj];
                        s1 += sRed[((ks + 1) * 4 + rb) * 64 + rj];
                        s2 += sRed[((ks + 2) * 4 + rb) * 64 + rj];
                        s3 += sRed[((ks + 3) * 4 + rb) * 64 + rj];
                    }
                    float k = (s0 + s1) + (s2 + s3);
                    float ynew;
                    if (mode == 1) {
                        rk1 = k;
                        ynew = fmaf(dt * (1.0f / 3.0f), rk1, rH);
                    } else if (mode == 2) {
                        rk2 = k;
                        ynew = fmaf(dt, rk2 - rk1 * (1.0f / 3.0f), rH);
                    } else if (mode == 3) {
                        rk3 = k;
                        ynew = fmaf(dt, rk1 - rk2 + rk3, rH);
                    } else {
                        rH = fmaf(dt * 0.125f, rk1 + 3.0f * (rk2 + rk3) + k, rH);
                        ynew = rH;
                        traj[(((size_t)(b0 + rb) * 64 + s) * 8 + step) * 64 + rj] = rH;
                    }
                    sY[rb][rj] = ynew;
                }
                __syncthreads();
            }
        }
    }
    if (t < 256) out[(size_t)(b0 + rb) * 64 + rj] = rH;
}

extern "C" void kernel_launch(void* const* d_in, const int* in_sizes, int n_in,
                              void* d_out, int out_size, void* d_ws, size_t ws_size,
                              hipStream_t stream) {
    const float* quat = (const float*)d_in[0];
    const float* W1   = (const float*)d_in[1];
    const float* b1   = (const float*)d_in[2];
    const float* W2   = (const float*)d_in[3];
    const float* b2   = (const float*)d_in[4];
    const float* W3   = (const float*)d_in[5];
    const float* b3   = (const float*)d_in[6];
    float* out = (float*)d_out;

    odernn_kernel<<<1024 / BT, NTHR, 0, stream>>>(quat, W1, b1, W2, b2, W3, b3, out);
}

// Round 3
// 5656.564 us; speedup vs baseline: 2.2004x; 1.4633x over previous
//
#include <hip/hip_runtime.h>
#include <math.h>

#define NTHR 512
#define BT 4

__device__ __forceinline__ float fast_tanh(float x) {
    float ax = fabsf(x);
    float e  = __expf(-2.0f * ax);                       // in (0,1], never overflows
    float r  = (1.0f - e) * __builtin_amdgcn_rcpf(1.0f + e);
    return copysignf(r, x);
}

__global__ __launch_bounds__(NTHR, 2)
void odernn_kernel(const float* __restrict__ quat,   // [1024][64][4]
                   const float* __restrict__ W1,     // [68][256]
                   const float* __restrict__ b1,     // [256]
                   const float* __restrict__ W2,     // [256][256]
                   const float* __restrict__ b2,     // [256]
                   const float* __restrict__ W3,     // [256][64]
                   const float* __restrict__ b3,     // [64]
                   float* __restrict__ out)          // [1024*64] hfinal, then [1024][64][8][64] traj
{
    // LDS: activations + partial sums only; ALL weights live in registers.
    __shared__ __align__(16) float sRed[8192];    // 32 KB, union: L2 partials [8][4][256] / L3 partials [32][4][64]
    __shared__ __align__(16) float sH1[4][256];   // 4 KB
    __shared__ __align__(16) float sH2[4][256];   // 4 KB
    __shared__ __align__(16) float sC1[4][256];   // 4 KB
    __shared__ __align__(16) float sY[4][64];     // 1 KB

    const int t = threadIdx.x;
    const int w = t >> 6;            // wave 0..7
    const int l = t & 63;            // lane
    const int b0 = blockIdx.x * BT;

    // ---- phase mappings (all dup-free weight ownership) ----
    // A (L1): lane-pair k-split: col j1a, k-half kha
    const int j1a = t >> 1;          // 0..255
    const int kha = (t & 1) * 32;    // k base: 0 or 32
    // B (L2): wave = k-slice (32 k), lane = j-quad
    const int kb2 = w * 32;
    // C (L2 reduce): col j1c, batch pair bc
    const int j1c = t & 255;
    const int bc  = (t >> 8) * 2;
    // D (L3): u3 = j-quad (16 quads = 64 cols), ks3 = k-slice (32 slices of 8)
    const int u3  = t & 15;
    const int ks3 = t >> 4;
    const int kb3 = ks3 * 8;
    // E (RK4, t<256): batch rb = wave, state dim rj = lane
    const int rb = w;                // valid for t<256
    const int rj = l;

    // ---- weights -> registers (loaded once) ----
    float w1r[32];                                   // W1h[kha+k][j1a]
    #pragma unroll
    for (int k = 0; k < 32; ++k) w1r[k] = W1[(kha + k) * 256 + j1a];

    float w2r[128];                                  // W2[kb2+k][l*4+jj]
    const float4* __restrict__ W2v4 = (const float4*)W2;
    #pragma unroll
    for (int k = 0; k < 32; ++k) {
        float4 v = W2v4[(size_t)(kb2 + k) * 64 + l];
        w2r[k * 4 + 0] = v.x; w2r[k * 4 + 1] = v.y;
        w2r[k * 4 + 2] = v.z; w2r[k * 4 + 3] = v.w;
    }
    float w3r[32];                                   // W3[kb3+k][u3*4+jj]
    #pragma unroll
    for (int k = 0; k < 8; ++k) {
        float4 v = *(const float4*)&W3[(kb3 + k) * 64 + u3 * 4];
        w3r[k * 4 + 0] = v.x; w3r[k * 4 + 1] = v.y;
        w3r[k * 4 + 2] = v.z; w3r[k * 4 + 3] = v.w;
    }
    float w1q[4];                                    // q-part of W1, col j1c (used t<256)
    #pragma unroll
    for (int m = 0; m < 4; ++m) w1q[m] = W1[(64 + m) * 256 + j1c];

    const float rb1  = b1[j1c];
    const float rb2c = b2[j1c];
    const float rb3e = b3[rj];

    float rH  = (rj == 0) ? 1.0f : 0.0f;   // meaningful for t<256
    float rk1 = 0.0f, rk2 = 0.0f, rk3 = 0.0f;
    if (t < 256) sY[rb][rj] = rH;

    const float dt = 1.0f / 7.0f;
    float* __restrict__ traj = out + 1024 * 64;

    for (int s = 0; s < 64; ++s) {
        // ---- per-token: c1 = b1 + q @ W1q ; record initial state ----
        if (t < 256) {
            float4 q0 = *(const float4*)&quat[((size_t)(b0 + 0) * 64 + s) * 4];
            float4 q1 = *(const float4*)&quat[((size_t)(b0 + 1) * 64 + s) * 4];
            float4 q2 = *(const float4*)&quat[((size_t)(b0 + 2) * 64 + s) * 4];
            float4 q3 = *(const float4*)&quat[((size_t)(b0 + 3) * 64 + s) * 4];
            sC1[0][t] = fmaf(q0.x, w1q[0], fmaf(q0.y, w1q[1], fmaf(q0.z, w1q[2], fmaf(q0.w, w1q[3], rb1))));
            sC1[1][t] = fmaf(q1.x, w1q[0], fmaf(q1.y, w1q[1], fmaf(q1.z, w1q[2], fmaf(q1.w, w1q[3], rb1))));
            sC1[2][t] = fmaf(q2.x, w1q[0], fmaf(q2.y, w1q[1], fmaf(q2.z, w1q[2], fmaf(q2.w, w1q[3], rb1))));
            sC1[3][t] = fmaf(q3.x, w1q[0], fmaf(q3.y, w1q[1], fmaf(q3.z, w1q[2], fmaf(q3.w, w1q[3], rb1))));
            traj[(((size_t)(b0 + rb) * 64 + s) * 8 + 0) * 64 + rj] = rH;
        }
        __syncthreads();

        for (int step = 1; step < 8; ++step) {
            #pragma unroll
            for (int mode = 1; mode <= 4; ++mode) {
                // ---------- A: h1 = tanh(y @ W1h + c1), k-split across lane pairs ----------
                {
                    float a0 = 0.0f, a1 = 0.0f, a2 = 0.0f, a3 = 0.0f;
                    const float4* y4 = (const float4*)&sY[0][0];
                    const int yb = (t & 1) * 8;      // float4 index of k-half
                    #pragma unroll
                    for (int k4 = 0; k4 < 8; ++k4) {
                        float4 y0 = y4[0 * 16 + yb + k4];
                        float4 y1 = y4[1 * 16 + yb + k4];
                        float4 y2 = y4[2 * 16 + yb + k4];
                        float4 y3 = y4[3 * 16 + yb + k4];
                        #pragma unroll
                        for (int r = 0; r < 4; ++r) {
                            float wv = w1r[k4 * 4 + r];
                            a0 = fmaf(((const float*)&y0)[r], wv, a0);
                            a1 = fmaf(((const float*)&y1)[r], wv, a1);
                            a2 = fmaf(((const float*)&y2)[r], wv, a2);
                            a3 = fmaf(((const float*)&y3)[r], wv, a3);
                        }
                    }
                    // lane-pair reduce (DPP, no LDS, no barrier)
                    a0 += __shfl_xor(a0, 1);
                    a1 += __shfl_xor(a1, 1);
                    a2 += __shfl_xor(a2, 1);
                    a3 += __shfl_xor(a3, 1);
                    // even lanes own batches {0,1}, odd own {2,3}
                    const int bw = (t & 1) * 2;
                    float vA = (t & 1) ? a2 : a0;
                    float vB = (t & 1) ? a3 : a1;
                    sH1[bw][j1a]     = fast_tanh(vA + sC1[bw][j1a]);
                    sH1[bw + 1][j1a] = fast_tanh(vB + sC1[bw + 1][j1a]);
                }
                __syncthreads();
                // ---------- B: layer-2 partials, W2 entirely in registers ----------
                {
                    float acc[4][4];
                    #pragma unroll
                    for (int bb = 0; bb < 4; ++bb)
                        #pragma unroll
                        for (int jj = 0; jj < 4; ++jj) acc[bb][jj] = 0.0f;
                    #pragma unroll
                    for (int k4 = 0; k4 < 8; ++k4) {
                        const int k = kb2 + k4 * 4;
                        float4 h0 = *(const float4*)&sH1[0][k];
                        float4 h1v = *(const float4*)&sH1[1][k];
                        float4 h2v = *(const float4*)&sH1[2][k];
                        float4 h3v = *(const float4*)&sH1[3][k];
                        #pragma unroll
                        for (int r = 0; r < 4; ++r) {
                            const int wi = (k4 * 4 + r) * 4;
                            float f0 = ((const float*)&h0)[r];
                            float f1 = ((const float*)&h1v)[r];
                            float f2 = ((const float*)&h2v)[r];
                            float f3 = ((const float*)&h3v)[r];
                            #pragma unroll
                            for (int jj = 0; jj < 4; ++jj) {
                                acc[0][jj] = fmaf(f0, w2r[wi + jj], acc[0][jj]);
                                acc[1][jj] = fmaf(f1, w2r[wi + jj], acc[1][jj]);
                                acc[2][jj] = fmaf(f2, w2r[wi + jj], acc[2][jj]);
                                acc[3][jj] = fmaf(f3, w2r[wi + jj], acc[3][jj]);
                            }
                        }
                    }
                    // partials: sRed as [8 ks][4 b][256 j]
                    #pragma unroll
                    for (int bb = 0; bb < 4; ++bb)
                        *(float4*)&sRed[w * 1024 + bb * 256 + l * 4] =
                            make_float4(acc[bb][0], acc[bb][1], acc[bb][2], acc[bb][3]);
                }
                __syncthreads();
                // ---------- C: layer-2 reduce + tanh ----------
                {
                    float v0 = rb2c, v1 = 0.0f, u0 = rb2c, u1 = 0.0f;
                    #pragma unroll
                    for (int ks = 0; ks < 8; ks += 2) {
                        v0 += sRed[ks * 1024 + bc * 256 + j1c];
                        u0 += sRed[ks * 1024 + (bc + 1) * 256 + j1c];
                        v1 += sRed[(ks + 1) * 1024 + bc * 256 + j1c];
                        u1 += sRed[(ks + 1) * 1024 + (bc + 1) * 256 + j1c];
                    }
                    sH2[bc][j1c]     = fast_tanh(v0 + v1);
                    sH2[bc + 1][j1c] = fast_tanh(u0 + u1);
                }
                __syncthreads();
                // ---------- D: layer-3 partials, W3 in registers ----------
                {
                    float acc[4][4];
                    #pragma unroll
                    for (int bb = 0; bb < 4; ++bb)
                        #pragma unroll
                        for (int jj = 0; jj < 4; ++jj) acc[bb][jj] = 0.0f;
                    #pragma unroll
                    for (int k4 = 0; k4 < 2; ++k4) {
                        const int k = kb3 + k4 * 4;
                        float4 h0 = *(const float4*)&sH2[0][k];
                        float4 h1v = *(const float4*)&sH2[1][k];
                        float4 h2v = *(const float4*)&sH2[2][k];
                        float4 h3v = *(const float4*)&sH2[3][k];
                        #pragma unroll
                        for (int r = 0; r < 4; ++r) {
                            const int wi = (k4 * 4 + r) * 4;
                            float f0 = ((const float*)&h0)[r];
                            float f1 = ((const float*)&h1v)[r];
                            float f2 = ((const float*)&h2v)[r];
                            float f3 = ((const float*)&h3v)[r];
                            #pragma unroll
                            for (int jj = 0; jj < 4; ++jj) {
                                acc[0][jj] = fmaf(f0, w3r[wi + jj], acc[0][jj]);
                                acc[1][jj] = fmaf(f1, w3r[wi + jj], acc[1][jj]);
                                acc[2][jj] = fmaf(f2, w3r[wi + jj], acc[2][jj]);
                                acc[3][jj] = fmaf(f3, w3r[wi + jj], acc[3][jj]);
                            }
                        }
                    }
                    // partials: sRed as [32 ks][4 b][64 j]
                    #pragma unroll
                    for (int bb = 0; bb < 4; ++bb)
                        *(float4*)&sRed[ks3 * 256 + bb * 64 + u3 * 4] =
                            make_float4(acc[bb][0], acc[bb][1], acc[bb][2], acc[bb][3]);
                }
                __syncthreads();
                // ---------- E: layer-3 reduce + RK4 (3/8-rule) ----------
                if (t < 256) {
                    float s0 = rb3e, s1 = 0.0f, s2 = 0.0f, s3 = 0.0f;
                    #pragma unroll
                    for (int ks = 0; ks < 32; ks += 4) {
                        s0 += sRed[(ks + 0) * 256 + rb * 64 + rj];
                        s1 += sRed[(ks + 1) * 256 + rb * 64 + rj];
                        s2 += sRed[(ks + 2) * 256 + rb * 64 + rj];
                        s3 += sRed[(ks + 3) * 256 + rb * 64 + rj];
                    }
                    float k = (s0 + s1) + (s2 + s3);
                    float ynew;
                    if (mode == 1) {
                        rk1 = k;
                        ynew = fmaf(dt * (1.0f / 3.0f), rk1, rH);
                    } else if (mode == 2) {
                        rk2 = k;
                        ynew = fmaf(dt, rk2 - rk1 * (1.0f / 3.0f), rH);
                    } else if (mode == 3) {
                        rk3 = k;
                        ynew = fmaf(dt, rk1 - rk2 + rk3, rH);
                    } else {
                        rH = fmaf(dt * 0.125f, rk1 + 3.0f * (rk2 + rk3) + k, rH);
                        ynew = rH;
                        traj[(((size_t)(b0 + rb) * 64 + s) * 8 + step) * 64 + rj] = rH;
                    }
                    sY[rb][rj] = ynew;
                }
                __syncthreads();
            }
        }
    }
    if (t < 256) out[(size_t)(b0 + rb) * 64 + rj] = rH;
}

extern "C" void kernel_launch(void* const* d_in, const int* in_sizes, int n_in,
                              void* d_out, int out_size, void* d_ws, size_t ws_size,
                              hipStream_t stream) {
    const float* quat = (const float*)d_in[0];
    const float* W1   = (const float*)d_in[1];
    const float* b1   = (const float*)d_in[2];
    const float* W2   = (const float*)d_in[3];
    const float* b2   = (const float*)d_in[4];
    const float* W3   = (const float*)d_in[5];
    const float* b3   = (const float*)d_in[6];
    float* out = (float*)d_out;

    odernn_kernel<<<1024 / BT, NTHR, 0, stream>>>(quat, W1, b1, W2, b2, W3, b3, out);
}